// Round 1
// baseline (3095.522 us; speedup 1.0000x reference)
//
#include <hip/hip_runtime.h>
#include <hip/hip_bf16.h>

// ---------------------------------------------------------------------------
// ResidualSAGEBlock: scatter-mean -> dual GEMM (+bias) -> BatchNorm -> +x -> ReLU
// N=100000, D=128, E=1600000 (sizes derived from in_sizes at runtime; D==128
// assumed for vectorization).
// ---------------------------------------------------------------------------

#define D128 128

// --- W transpose: WT[k*128+d] = W[d*128+k] (two 128x128 matrices) ----------
__global__ void transpose_w_kernel(const float* __restrict__ Wl,
                                   const float* __restrict__ Wr,
                                   float* __restrict__ WlT,
                                   float* __restrict__ WrT) {
    int idx = blockIdx.x * 256 + threadIdx.x;        // 0 .. 32767
    int m   = idx >> 14;                             // matrix select
    int r   = idx & 16383;
    int k   = r >> 7, d = r & 127;
    if (m == 0) WlT[r] = Wl[d * D128 + k];
    else        WrT[r] = Wr[d * D128 + k];
}

// --- scatter-add: 32 threads per edge, float4 gather + 4 atomics -----------
__global__ __launch_bounds__(256) void scatter_kernel(
    const float* __restrict__ x, const int* __restrict__ src,
    const int* __restrict__ dst, float* __restrict__ agg,
    float* __restrict__ cnt, long long E) {
    long long gid = (long long)blockIdx.x * 256 + threadIdx.x;
    long long e   = gid >> 5;
    if (e >= E) return;
    int j = (int)(gid & 31);
    int s = src[e];
    int t = dst[e];
    float4 v = ((const float4*)(x + (long long)s * D128))[j];
    float* a = agg + (long long)t * D128 + j * 4;
    atomicAdd(a + 0, v.x);
    atomicAdd(a + 1, v.y);
    atomicAdd(a + 2, v.z);
    atomicAdd(a + 3, v.w);
    if (j == 0) atomicAdd(cnt + t, 1.0f);
}

// --- dual GEMM: h[n][d] = sum_k a[n][k]*WlT[k][d] + x[n][k]*WrT[k][d] + bl[d]
// 8 rows per block, 256 threads: r = tid>>5 (row), cg = tid&31 (4 cols each).
__global__ __launch_bounds__(256) void gemm_kernel(
    const float* __restrict__ agg, const float* __restrict__ cnt,
    const float* __restrict__ x, const float* __restrict__ WlT,
    const float* __restrict__ WrT, const float* __restrict__ bl,
    float* __restrict__ h, int N) {
    __shared__ float sWl[32 * D128];
    __shared__ float sWr[32 * D128];
    __shared__ float sA[8][D128];
    __shared__ float sX[8][D128];

    int tid = threadIdx.x;
    int n0  = blockIdx.x * 8;

    // stage A (mean-normalized) and X rows: 1024 floats each, 4/thread
    {
        int j   = tid * 4;
        int row = j >> 7, col = j & 127;
        int n   = n0 + row;
        if (n < N) {
            float inv = 1.0f / fmaxf(cnt[n], 1.0f);
            float4 a  = *(const float4*)(agg + (size_t)n * D128 + col);
            a.x *= inv; a.y *= inv; a.z *= inv; a.w *= inv;
            *(float4*)&sA[row][col] = a;
            *(float4*)&sX[row][col] = *(const float4*)(x + (size_t)n * D128 + col);
        } else {
            *(float4*)&sA[row][col] = make_float4(0.f, 0.f, 0.f, 0.f);
            *(float4*)&sX[row][col] = make_float4(0.f, 0.f, 0.f, 0.f);
        }
    }

    int cg = tid & 31, r = tid >> 5;
    int d  = cg * 4;
    float4 acc = *(const float4*)(bl + d);

    for (int k0 = 0; k0 < D128; k0 += 32) {
        __syncthreads();
        // stage 32x128 W tiles (4096 floats each), 16 floats/thread
        for (int j = tid * 4; j < 32 * D128; j += 1024) {
            *(float4*)&sWl[j] = *(const float4*)(WlT + k0 * D128 + j);
            *(float4*)&sWr[j] = *(const float4*)(WrT + k0 * D128 + j);
        }
        __syncthreads();
#pragma unroll
        for (int k = 0; k < 32; ++k) {
            float a  = sA[r][k0 + k];
            float xx = sX[r][k0 + k];
            float4 wl = *(const float4*)&sWl[k * D128 + d];
            float4 wr = *(const float4*)&sWr[k * D128 + d];
            acc.x = fmaf(a, wl.x, acc.x); acc.y = fmaf(a, wl.y, acc.y);
            acc.z = fmaf(a, wl.z, acc.z); acc.w = fmaf(a, wl.w, acc.w);
            acc.x = fmaf(xx, wr.x, acc.x); acc.y = fmaf(xx, wr.y, acc.y);
            acc.z = fmaf(xx, wr.z, acc.z); acc.w = fmaf(xx, wr.w, acc.w);
        }
    }

    int n = n0 + r;
    if (n < N) *(float4*)(h + (size_t)n * D128 + d) = acc;
}

// --- BN stats: per-feature sum and sumsq over N rows -----------------------
__global__ __launch_bounds__(256) void stats_kernel(
    const float* __restrict__ h, float* __restrict__ stats, int N) {
    int d    = threadIdx.x & 127;
    int half = threadIdx.x >> 7;
    int chunk = (N + gridDim.x - 1) / gridDim.x;
    int n0 = blockIdx.x * chunk;
    int n1 = min(n0 + chunk, N);
    float s = 0.f, ss = 0.f;
    for (int n = n0 + half; n < n1; n += 2) {
        float v = h[(size_t)n * D128 + d];
        s += v;
        ss += v * v;
    }
    __shared__ float r1[2][D128];
    __shared__ float r2[2][D128];
    r1[half][d] = s;
    r2[half][d] = ss;
    __syncthreads();
    if (half == 0) {
        atomicAdd(&stats[d],        s  + r1[1][d]);
        atomicAdd(&stats[D128 + d], ss + r2[1][d]);
    }
}

// --- BN params: scale/shift per feature ------------------------------------
__global__ void bnparam_kernel(const float* __restrict__ stats,
                               const float* __restrict__ gamma,
                               const float* __restrict__ beta,
                               float* __restrict__ scl, float* __restrict__ shf,
                               float invN) {
    int d = threadIdx.x;
    float mean = stats[d] * invN;
    float var  = stats[D128 + d] * invN - mean * mean;
    float istd = rsqrtf(var + 1e-5f);
    float sc   = gamma[d] * istd;
    scl[d] = sc;
    shf[d] = beta[d] - mean * sc;
}

// --- finalize: out = relu(h*scale + shift + x), float4, in-place on d_out --
__global__ __launch_bounds__(256) void finalize_kernel(
    const float* __restrict__ h, const float* __restrict__ x,
    const float* __restrict__ scl, const float* __restrict__ shf,
    float* __restrict__ out, long long total4) {
    long long i = (long long)blockIdx.x * 256 + threadIdx.x;
    if (i >= total4) return;
    int d = (int)((i * 4) & 127);
    float4 hv = ((const float4*)h)[i];
    float4 xv = ((const float4*)x)[i];
    float4 sc = *(const float4*)(scl + d);
    float4 sh = *(const float4*)(shf + d);
    float4 o;
    o.x = fmaxf(fmaf(hv.x, sc.x, sh.x) + xv.x, 0.f);
    o.y = fmaxf(fmaf(hv.y, sc.y, sh.y) + xv.y, 0.f);
    o.z = fmaxf(fmaf(hv.z, sc.z, sh.z) + xv.z, 0.f);
    o.w = fmaxf(fmaf(hv.w, sc.w, sh.w) + xv.w, 0.f);
    ((float4*)out)[i] = o;
}

extern "C" void kernel_launch(void* const* d_in, const int* in_sizes, int n_in,
                              void* d_out, int out_size, void* d_ws, size_t ws_size,
                              hipStream_t stream) {
    const float* x     = (const float*)d_in[0];
    const int*   eidx  = (const int*)d_in[1];
    const float* W_l   = (const float*)d_in[2];
    const float* b_l   = (const float*)d_in[3];
    const float* W_r   = (const float*)d_in[4];
    const float* gamma = (const float*)d_in[5];
    const float* beta  = (const float*)d_in[6];

    const int D = in_sizes[3];            // 128
    const int N = in_sizes[0] / D;        // 100000
    const long long E = in_sizes[1] / 2;  // 1600000

    const int* src = eidx;
    const int* dst = eidx + E;

    // workspace layout (floats)
    float* ws    = (float*)d_ws;
    float* agg   = ws;                               // N*128
    float* cnt   = agg + (size_t)N * D128;           // N
    float* stats = cnt + N;                          // 256
    float* WlT   = stats + 256;                      // 16384
    float* WrT   = WlT + 16384;                      // 16384
    float* scl   = WrT + 16384;                      // 128
    float* shf   = scl + D128;                       // 128

    float* h = (float*)d_out;                        // h lives in d_out

    // zero agg + cnt + stats (contiguous)
    size_t zero_bytes = ((size_t)N * D128 + N + 256) * sizeof(float);
    hipMemsetAsync(d_ws, 0, zero_bytes, stream);

    // transpose weights
    transpose_w_kernel<<<128, 256, 0, stream>>>(W_l, W_r, WlT, WrT);

    // scatter-add
    {
        long long threads = E * 32;
        int blocks = (int)((threads + 255) / 256);
        scatter_kernel<<<blocks, 256, 0, stream>>>(x, src, dst, agg, cnt, E);
    }

    // dual GEMM -> h (in d_out)
    {
        int blocks = (N + 7) / 8;
        gemm_kernel<<<blocks, 256, 0, stream>>>(agg, cnt, x, WlT, WrT, b_l, h, N);
    }

    // BN stats
    stats_kernel<<<512, 256, 0, stream>>>(h, stats, N);

    // BN scale/shift
    bnparam_kernel<<<1, 128, 0, stream>>>(stats, gamma, beta, scl, shf, 1.0f / (float)N);

    // finalize (in-place on d_out)
    {
        long long total4 = (long long)N * D128 / 4;
        int blocks = (int)((total4 + 255) / 256);
        finalize_kernel<<<blocks, 256, 0, stream>>>(h, x, scl, shf, (float*)d_out, total4);
    }
}

// Round 2
// 812.582 us; speedup vs baseline: 3.8095x; 3.8095x over previous
//
#include <hip/hip_runtime.h>
#include <hip/hip_bf16.h>

// ---------------------------------------------------------------------------
// ResidualSAGEBlock: CSR-build (counting sort by dst) -> fused gather-mean +
// dual GEMM -> BatchNorm -> +x -> ReLU.
// N=100000, D=128, E=1600000. R2: replaced float-atomic scatter (3.3 GB HBM
// write amplification, 2755 us) with CSR gather.
// ---------------------------------------------------------------------------

#define D128 128

// --- W transpose: WT[k*128+d] = W[d*128+k] (two 128x128 matrices) ----------
__global__ void transpose_w_kernel(const float* __restrict__ Wl,
                                   const float* __restrict__ Wr,
                                   float* __restrict__ WlT,
                                   float* __restrict__ WrT) {
    int idx = blockIdx.x * 256 + threadIdx.x;        // 0 .. 32767
    int m   = idx >> 14;                             // matrix select
    int r   = idx & 16383;
    int k   = r >> 7, d = r & 127;
    if (m == 0) WlT[r] = Wl[d * D128 + k];
    else        WrT[r] = Wr[d * D128 + k];
}

// --- histogram of dst ------------------------------------------------------
__global__ __launch_bounds__(256) void hist_kernel(const int* __restrict__ dst,
                                                   int* __restrict__ deg, int E) {
    int i = blockIdx.x * 256 + threadIdx.x;
    if (i < E) atomicAdd(&deg[dst[i]], 1);
}

// --- exclusive scan over deg -> offs[N+1], duplicate into cursor -----------
__global__ __launch_bounds__(1024) void scan_kernel(const int* __restrict__ deg,
                                                    int* __restrict__ offs,
                                                    int* __restrict__ cursor, int N) {
    int t = threadIdx.x;
    int C = (N + 1023) >> 10;
    int c0 = t * C, c1 = min(c0 + C, N);
    int s = 0;
    for (int i = c0; i < c1; ++i) s += deg[i];
    __shared__ int buf[2][1024];
    buf[0][t] = s;
    __syncthreads();
    int pi = 0;
    for (int off = 1; off < 1024; off <<= 1) {
        int v = buf[pi][t];
        if (t >= off) v += buf[pi][t - off];
        buf[pi ^ 1][t] = v;
        __syncthreads();
        pi ^= 1;
    }
    int run = buf[pi][t] - s;          // exclusive prefix
    for (int i = c0; i < c1; ++i) {
        offs[i] = run;
        cursor[i] = run;
        run += deg[i];
    }
    if (t == 1023) offs[N] = buf[pi][1023];
}

// --- CSR fill: csr[pos] = src, pos = cursor[dst]++ -------------------------
__global__ __launch_bounds__(256) void csr_kernel(const int* __restrict__ src,
                                                  const int* __restrict__ dst,
                                                  int* __restrict__ cursor,
                                                  int* __restrict__ csr, int E) {
    int i = blockIdx.x * 256 + threadIdx.x;
    if (i < E) {
        int pos = atomicAdd(&cursor[dst[i]], 1);
        csr[pos] = src[i];
    }
}

// --- fused gather-mean + dual GEMM -----------------------------------------
// 16 rows/block, 256 threads. lane = tid&31 (feature/col group, 4 floats),
// rg = tid>>5 (0..7) owns rows rg and rg+8.
__global__ __launch_bounds__(256) void gemm_kernel(
    const int* __restrict__ offs, const int* __restrict__ csr,
    const float* __restrict__ x, const float* __restrict__ WlT,
    const float* __restrict__ WrT, const float* __restrict__ bl,
    float* __restrict__ h, int N) {
    __shared__ float sWl[32 * D128];
    __shared__ float sWr[32 * D128];
    __shared__ float sA[16][D128];
    __shared__ float sX[16][D128];

    int tid  = threadIdx.x;
    int lane = tid & 31;
    int rg   = tid >> 5;
    int n0   = blockIdx.x * 16;

    // gather-mean rows rg and rg+8 into sA; stage x rows into sX
#pragma unroll
    for (int rr = 0; rr < 2; ++rr) {
        int row = rg + rr * 8;
        int n   = n0 + row;
        float4 acc  = make_float4(0.f, 0.f, 0.f, 0.f);
        float4 acc2 = make_float4(0.f, 0.f, 0.f, 0.f);
        float4 xv   = make_float4(0.f, 0.f, 0.f, 0.f);
        if (n < N) {
            int beg = offs[n], end = offs[n + 1];
            int k = beg;
            for (; k + 1 < end; k += 2) {
                int s0 = csr[k], s1 = csr[k + 1];
                float4 v0 = ((const float4*)(x + (size_t)s0 * D128))[lane];
                float4 v1 = ((const float4*)(x + (size_t)s1 * D128))[lane];
                acc.x  += v0.x; acc.y  += v0.y; acc.z  += v0.z; acc.w  += v0.w;
                acc2.x += v1.x; acc2.y += v1.y; acc2.z += v1.z; acc2.w += v1.w;
            }
            if (k < end) {
                int s0 = csr[k];
                float4 v0 = ((const float4*)(x + (size_t)s0 * D128))[lane];
                acc.x += v0.x; acc.y += v0.y; acc.z += v0.z; acc.w += v0.w;
            }
            float inv = (end > beg) ? 1.0f / (float)(end - beg) : 0.f;
            acc.x = (acc.x + acc2.x) * inv;
            acc.y = (acc.y + acc2.y) * inv;
            acc.z = (acc.z + acc2.z) * inv;
            acc.w = (acc.w + acc2.w) * inv;
            xv = ((const float4*)(x + (size_t)n * D128))[lane];
        }
        *(float4*)&sA[row][lane * 4] = acc;
        *(float4*)&sX[row][lane * 4] = xv;
    }

    int d = lane * 4;
    float4 acc0 = *(const float4*)(bl + d);   // row rg
    float4 acc1 = acc0;                       // row rg+8

    for (int k0 = 0; k0 < D128; k0 += 32) {
        __syncthreads();   // first iter: gather done; later: compute done
        for (int j = tid * 4; j < 32 * D128; j += 1024) {
            *(float4*)&sWl[j] = *(const float4*)(WlT + k0 * D128 + j);
            *(float4*)&sWr[j] = *(const float4*)(WrT + k0 * D128 + j);
        }
        __syncthreads();
#pragma unroll
        for (int kk = 0; kk < 32; kk += 4) {
            float4 a0 = *(const float4*)&sA[rg][k0 + kk];
            float4 a1 = *(const float4*)&sA[rg + 8][k0 + kk];
            float4 x0 = *(const float4*)&sX[rg][k0 + kk];
            float4 x1 = *(const float4*)&sX[rg + 8][k0 + kk];
#pragma unroll
            for (int j = 0; j < 4; ++j) {
                float4 wl = *(const float4*)&sWl[(kk + j) * D128 + d];
                float4 wr = *(const float4*)&sWr[(kk + j) * D128 + d];
                float av0 = ((float*)&a0)[j], xv0 = ((float*)&x0)[j];
                float av1 = ((float*)&a1)[j], xv1 = ((float*)&x1)[j];
                acc0.x = fmaf(av0, wl.x, acc0.x); acc0.y = fmaf(av0, wl.y, acc0.y);
                acc0.z = fmaf(av0, wl.z, acc0.z); acc0.w = fmaf(av0, wl.w, acc0.w);
                acc0.x = fmaf(xv0, wr.x, acc0.x); acc0.y = fmaf(xv0, wr.y, acc0.y);
                acc0.z = fmaf(xv0, wr.z, acc0.z); acc0.w = fmaf(xv0, wr.w, acc0.w);
                acc1.x = fmaf(av1, wl.x, acc1.x); acc1.y = fmaf(av1, wl.y, acc1.y);
                acc1.z = fmaf(av1, wl.z, acc1.z); acc1.w = fmaf(av1, wl.w, acc1.w);
                acc1.x = fmaf(xv1, wr.x, acc1.x); acc1.y = fmaf(xv1, wr.y, acc1.y);
                acc1.z = fmaf(xv1, wr.z, acc1.z); acc1.w = fmaf(xv1, wr.w, acc1.w);
            }
        }
    }

    int n = n0 + rg;
    if (n < N) *(float4*)(h + (size_t)n * D128 + d) = acc0;
    n = n0 + rg + 8;
    if (n < N) *(float4*)(h + (size_t)n * D128 + d) = acc1;
}

// --- BN stats: per-feature sum and sumsq over N rows -----------------------
__global__ __launch_bounds__(256) void stats_kernel(
    const float* __restrict__ h, float* __restrict__ stats, int N) {
    int d    = threadIdx.x & 127;
    int half = threadIdx.x >> 7;
    int chunk = (N + gridDim.x - 1) / gridDim.x;
    int n0 = blockIdx.x * chunk;
    int n1 = min(n0 + chunk, N);
    float s = 0.f, ss = 0.f;
    for (int n = n0 + half; n < n1; n += 2) {
        float v = h[(size_t)n * D128 + d];
        s += v;
        ss += v * v;
    }
    __shared__ float r1[2][D128];
    __shared__ float r2[2][D128];
    r1[half][d] = s;
    r2[half][d] = ss;
    __syncthreads();
    if (half == 0) {
        atomicAdd(&stats[d],        s  + r1[1][d]);
        atomicAdd(&stats[D128 + d], ss + r2[1][d]);
    }
}

// --- BN params: scale/shift per feature ------------------------------------
__global__ void bnparam_kernel(const float* __restrict__ stats,
                               const float* __restrict__ gamma,
                               const float* __restrict__ beta,
                               float* __restrict__ scl, float* __restrict__ shf,
                               float invN) {
    int d = threadIdx.x;
    float mean = stats[d] * invN;
    float var  = stats[D128 + d] * invN - mean * mean;
    float istd = rsqrtf(var + 1e-5f);
    float sc   = gamma[d] * istd;
    scl[d] = sc;
    shf[d] = beta[d] - mean * sc;
}

// --- finalize: out = relu(h*scale + shift + x), float4, in-place on d_out --
__global__ __launch_bounds__(256) void finalize_kernel(
    const float* __restrict__ h, const float* __restrict__ x,
    const float* __restrict__ scl, const float* __restrict__ shf,
    float* __restrict__ out, long long total4) {
    long long i = (long long)blockIdx.x * 256 + threadIdx.x;
    if (i >= total4) return;
    int d = (int)((i * 4) & 127);
    float4 hv = ((const float4*)h)[i];
    float4 xv = ((const float4*)x)[i];
    float4 sc = *(const float4*)(scl + d);
    float4 sh = *(const float4*)(shf + d);
    float4 o;
    o.x = fmaxf(fmaf(hv.x, sc.x, sh.x) + xv.x, 0.f);
    o.y = fmaxf(fmaf(hv.y, sc.y, sh.y) + xv.y, 0.f);
    o.z = fmaxf(fmaf(hv.z, sc.z, sh.z) + xv.z, 0.f);
    o.w = fmaxf(fmaf(hv.w, sc.w, sh.w) + xv.w, 0.f);
    ((float4*)out)[i] = o;
}

extern "C" void kernel_launch(void* const* d_in, const int* in_sizes, int n_in,
                              void* d_out, int out_size, void* d_ws, size_t ws_size,
                              hipStream_t stream) {
    const float* x     = (const float*)d_in[0];
    const int*   eidx  = (const int*)d_in[1];
    const float* W_l   = (const float*)d_in[2];
    const float* b_l   = (const float*)d_in[3];
    const float* W_r   = (const float*)d_in[4];
    const float* gamma = (const float*)d_in[5];
    const float* beta  = (const float*)d_in[6];

    const int D = in_sizes[3];            // 128
    const int N = in_sizes[0] / D;        // 100000
    const int E = in_sizes[1] / 2;        // 1600000

    const int* src = eidx;
    const int* dst = eidx + E;

    // workspace layout (4-byte units)
    int*   deg    = (int*)d_ws;                     // N
    float* stats  = (float*)d_ws + N;               // 256
    int*   offs   = (int*)d_ws + N + 256;           // N+1
    int*   cursor = offs + N + 1;                   // N
    int*   csr    = cursor + N;                     // E
    float* WlT    = (float*)(csr + E);              // 16384
    float* WrT    = WlT + 16384;                    // 16384
    float* scl    = WrT + 16384;                    // 128
    float* shf    = scl + D128;                     // 128

    float* h = (float*)d_out;                       // h lives in d_out

    // zero deg + stats (contiguous)
    hipMemsetAsync(d_ws, 0, (size_t)(N + 256) * sizeof(int), stream);

    transpose_w_kernel<<<128, 256, 0, stream>>>(W_l, W_r, WlT, WrT);

    hist_kernel<<<(E + 255) / 256, 256, 0, stream>>>(dst, deg, E);

    scan_kernel<<<1, 1024, 0, stream>>>(deg, offs, cursor, N);

    csr_kernel<<<(E + 255) / 256, 256, 0, stream>>>(src, dst, cursor, csr, E);

    gemm_kernel<<<(N + 15) / 16, 256, 0, stream>>>(offs, csr, x, WlT, WrT, b_l, h, N);

    stats_kernel<<<512, 256, 0, stream>>>(h, stats, N);

    bnparam_kernel<<<1, 128, 0, stream>>>(stats, gamma, beta, scl, shf, 1.0f / (float)N);

    {
        long long total4 = (long long)N * D128 / 4;
        finalize_kernel<<<(int)((total4 + 255) / 256), 256, 0, stream>>>(
            h, x, scl, shf, (float*)d_out, total4);
    }
}

// Round 3
// 761.077 us; speedup vs baseline: 4.0673x; 1.0677x over previous
//
#include <hip/hip_runtime.h>
#include <hip/hip_bf16.h>

// ---------------------------------------------------------------------------
// ResidualSAGEBlock: CSR-build (counting sort by dst) -> fused gather-mean +
// dual GEMM -> BatchNorm -> +x -> ReLU.
// N=100000, D=128, E=1600000.
// R2: CSR gather replaced float-atomic scatter (3.3 GB write amp): 3095->812us.
// R3: gemm LDS 48->32KB (W chunked by 16k) => 5 blocks/CU; gather unroll x4.
// ---------------------------------------------------------------------------

#define D128 128

// --- W transpose: WT[k*128+d] = W[d*128+k] (two 128x128 matrices) ----------
__global__ void transpose_w_kernel(const float* __restrict__ Wl,
                                   const float* __restrict__ Wr,
                                   float* __restrict__ WlT,
                                   float* __restrict__ WrT) {
    int idx = blockIdx.x * 256 + threadIdx.x;        // 0 .. 32767
    int m   = idx >> 14;                             // matrix select
    int r   = idx & 16383;
    int k   = r >> 7, d = r & 127;
    if (m == 0) WlT[r] = Wl[d * D128 + k];
    else        WrT[r] = Wr[d * D128 + k];
}

// --- histogram of dst (4 edges/thread, int4 loads) -------------------------
__global__ __launch_bounds__(256) void hist_kernel(const int* __restrict__ dst,
                                                   int* __restrict__ deg, int E) {
    int i = (blockIdx.x * 256 + threadIdx.x) * 4;
    if (i + 3 < E) {
        int4 d4 = *(const int4*)(dst + i);
        atomicAdd(&deg[d4.x], 1);
        atomicAdd(&deg[d4.y], 1);
        atomicAdd(&deg[d4.z], 1);
        atomicAdd(&deg[d4.w], 1);
    } else {
        for (int j = i; j < E; ++j) atomicAdd(&deg[dst[j]], 1);
    }
}

// --- exclusive scan over deg -> offs[N+1], duplicate into cursor -----------
__global__ __launch_bounds__(1024) void scan_kernel(const int* __restrict__ deg,
                                                    int* __restrict__ offs,
                                                    int* __restrict__ cursor, int N) {
    int t = threadIdx.x;
    int C = (N + 1023) >> 10;
    int c0 = t * C, c1 = min(c0 + C, N);
    int s = 0;
    for (int i = c0; i < c1; ++i) s += deg[i];
    __shared__ int buf[2][1024];
    buf[0][t] = s;
    __syncthreads();
    int pi = 0;
    for (int off = 1; off < 1024; off <<= 1) {
        int v = buf[pi][t];
        if (t >= off) v += buf[pi][t - off];
        buf[pi ^ 1][t] = v;
        __syncthreads();
        pi ^= 1;
    }
    int run = buf[pi][t] - s;          // exclusive prefix
    for (int i = c0; i < c1; ++i) {
        offs[i] = run;
        cursor[i] = run;
        run += deg[i];
    }
    if (t == 1023) offs[N] = buf[pi][1023];
}

// --- CSR fill: csr[pos] = src, pos = cursor[dst]++ (4 edges/thread) --------
__global__ __launch_bounds__(256) void csr_kernel(const int* __restrict__ src,
                                                  const int* __restrict__ dst,
                                                  int* __restrict__ cursor,
                                                  int* __restrict__ csr, int E) {
    int i = (blockIdx.x * 256 + threadIdx.x) * 4;
    if (i + 3 < E) {
        int4 d4 = *(const int4*)(dst + i);
        int4 s4 = *(const int4*)(src + i);
        csr[atomicAdd(&cursor[d4.x], 1)] = s4.x;
        csr[atomicAdd(&cursor[d4.y], 1)] = s4.y;
        csr[atomicAdd(&cursor[d4.z], 1)] = s4.z;
        csr[atomicAdd(&cursor[d4.w], 1)] = s4.w;
    } else {
        for (int j = i; j < E; ++j) csr[atomicAdd(&cursor[dst[j]], 1)] = src[j];
    }
}

// --- fused gather-mean + dual GEMM -----------------------------------------
// 16 rows/block, 256 threads. lane = tid&31 (feature/col group, 4 floats),
// rg = tid>>5 (0..7) owns rows rg and rg+8.
// LDS = 32 KB (sW chunk 16k x 2 mats = 16 KB, sA+sX = 16 KB) -> 5 blocks/CU.
__global__ __launch_bounds__(256, 5) void gemm_kernel(
    const int* __restrict__ offs, const int* __restrict__ csr,
    const float* __restrict__ x, const float* __restrict__ WlT,
    const float* __restrict__ WrT, const float* __restrict__ bl,
    float* __restrict__ h, int N) {
    __shared__ float sWl[16 * D128];
    __shared__ float sWr[16 * D128];
    __shared__ float sA[16][D128];
    __shared__ float sX[16][D128];

    int tid  = threadIdx.x;
    int lane = tid & 31;
    int rg   = tid >> 5;
    int n0   = blockIdx.x * 16;

    // gather-mean rows rg and rg+8 into sA; stage x rows into sX
#pragma unroll
    for (int rr = 0; rr < 2; ++rr) {
        int row = rg + rr * 8;
        int n   = n0 + row;
        float4 a0 = make_float4(0.f, 0.f, 0.f, 0.f);
        float4 a1 = a0, a2 = a0, a3 = a0;
        float4 xv = a0;
        if (n < N) {
            int beg = offs[n], end = offs[n + 1];
            int k = beg;
            for (; k + 3 < end; k += 4) {
                int s0 = csr[k], s1 = csr[k + 1], s2 = csr[k + 2], s3 = csr[k + 3];
                float4 v0 = ((const float4*)(x + (size_t)s0 * D128))[lane];
                float4 v1 = ((const float4*)(x + (size_t)s1 * D128))[lane];
                float4 v2 = ((const float4*)(x + (size_t)s2 * D128))[lane];
                float4 v3 = ((const float4*)(x + (size_t)s3 * D128))[lane];
                a0.x += v0.x; a0.y += v0.y; a0.z += v0.z; a0.w += v0.w;
                a1.x += v1.x; a1.y += v1.y; a1.z += v1.z; a1.w += v1.w;
                a2.x += v2.x; a2.y += v2.y; a2.z += v2.z; a2.w += v2.w;
                a3.x += v3.x; a3.y += v3.y; a3.z += v3.z; a3.w += v3.w;
            }
            for (; k < end; ++k) {
                int s0 = csr[k];
                float4 v0 = ((const float4*)(x + (size_t)s0 * D128))[lane];
                a0.x += v0.x; a0.y += v0.y; a0.z += v0.z; a0.w += v0.w;
            }
            float inv = (end > beg) ? 1.0f / (float)(end - beg) : 0.f;
            a0.x = ((a0.x + a1.x) + (a2.x + a3.x)) * inv;
            a0.y = ((a0.y + a1.y) + (a2.y + a3.y)) * inv;
            a0.z = ((a0.z + a1.z) + (a2.z + a3.z)) * inv;
            a0.w = ((a0.w + a1.w) + (a2.w + a3.w)) * inv;
            xv = ((const float4*)(x + (size_t)n * D128))[lane];
        }
        *(float4*)&sA[row][lane * 4] = a0;
        *(float4*)&sX[row][lane * 4] = xv;
    }

    int d = lane * 4;
    float4 acc0 = *(const float4*)(bl + d);   // row rg
    float4 acc1 = acc0;                       // row rg+8

    for (int k0 = 0; k0 < D128; k0 += 16) {
        __syncthreads();   // first iter: gather done; later: compute done
        // stage 16x128 W tiles (2048 floats each), 8 floats/thread/matrix
        for (int j = tid * 4; j < 16 * D128; j += 1024) {
            *(float4*)&sWl[j] = *(const float4*)(WlT + k0 * D128 + j);
            *(float4*)&sWr[j] = *(const float4*)(WrT + k0 * D128 + j);
        }
        __syncthreads();
#pragma unroll
        for (int kk = 0; kk < 16; kk += 4) {
            float4 a0 = *(const float4*)&sA[rg][k0 + kk];
            float4 a1 = *(const float4*)&sA[rg + 8][k0 + kk];
            float4 x0 = *(const float4*)&sX[rg][k0 + kk];
            float4 x1 = *(const float4*)&sX[rg + 8][k0 + kk];
#pragma unroll
            for (int j = 0; j < 4; ++j) {
                float4 wl = *(const float4*)&sWl[(kk + j) * D128 + d];
                float4 wr = *(const float4*)&sWr[(kk + j) * D128 + d];
                float av0 = ((float*)&a0)[j], xv0 = ((float*)&x0)[j];
                float av1 = ((float*)&a1)[j], xv1 = ((float*)&x1)[j];
                acc0.x = fmaf(av0, wl.x, acc0.x); acc0.y = fmaf(av0, wl.y, acc0.y);
                acc0.z = fmaf(av0, wl.z, acc0.z); acc0.w = fmaf(av0, wl.w, acc0.w);
                acc0.x = fmaf(xv0, wr.x, acc0.x); acc0.y = fmaf(xv0, wr.y, acc0.y);
                acc0.z = fmaf(xv0, wr.z, acc0.z); acc0.w = fmaf(xv0, wr.w, acc0.w);
                acc1.x = fmaf(av1, wl.x, acc1.x); acc1.y = fmaf(av1, wl.y, acc1.y);
                acc1.z = fmaf(av1, wl.z, acc1.z); acc1.w = fmaf(av1, wl.w, acc1.w);
                acc1.x = fmaf(xv1, wr.x, acc1.x); acc1.y = fmaf(xv1, wr.y, acc1.y);
                acc1.z = fmaf(xv1, wr.z, acc1.z); acc1.w = fmaf(xv1, wr.w, acc1.w);
            }
        }
    }

    int n = n0 + rg;
    if (n < N) *(float4*)(h + (size_t)n * D128 + d) = acc0;
    n = n0 + rg + 8;
    if (n < N) *(float4*)(h + (size_t)n * D128 + d) = acc1;
}

// --- BN stats: per-feature sum and sumsq over N rows -----------------------
__global__ __launch_bounds__(256) void stats_kernel(
    const float* __restrict__ h, float* __restrict__ stats, int N) {
    int d    = threadIdx.x & 127;
    int half = threadIdx.x >> 7;
    int chunk = (N + gridDim.x - 1) / gridDim.x;
    int n0 = blockIdx.x * chunk;
    int n1 = min(n0 + chunk, N);
    float s = 0.f, ss = 0.f;
    for (int n = n0 + half; n < n1; n += 2) {
        float v = h[(size_t)n * D128 + d];
        s += v;
        ss += v * v;
    }
    __shared__ float r1[2][D128];
    __shared__ float r2[2][D128];
    r1[half][d] = s;
    r2[half][d] = ss;
    __syncthreads();
    if (half == 0) {
        atomicAdd(&stats[d],        s  + r1[1][d]);
        atomicAdd(&stats[D128 + d], ss + r2[1][d]);
    }
}

// --- BN params: scale/shift per feature ------------------------------------
__global__ void bnparam_kernel(const float* __restrict__ stats,
                               const float* __restrict__ gamma,
                               const float* __restrict__ beta,
                               float* __restrict__ scl, float* __restrict__ shf,
                               float invN) {
    int d = threadIdx.x;
    float mean = stats[d] * invN;
    float var  = stats[D128 + d] * invN - mean * mean;
    float istd = rsqrtf(var + 1e-5f);
    float sc   = gamma[d] * istd;
    scl[d] = sc;
    shf[d] = beta[d] - mean * sc;
}

// --- finalize: out = relu(h*scale + shift + x), float4, in-place on d_out --
__global__ __launch_bounds__(256) void finalize_kernel(
    const float* __restrict__ h, const float* __restrict__ x,
    const float* __restrict__ scl, const float* __restrict__ shf,
    float* __restrict__ out, long long total4) {
    long long i = (long long)blockIdx.x * 256 + threadIdx.x;
    if (i >= total4) return;
    int d = (int)((i * 4) & 127);
    float4 hv = ((const float4*)h)[i];
    float4 xv = ((const float4*)x)[i];
    float4 sc = *(const float4*)(scl + d);
    float4 sh = *(const float4*)(shf + d);
    float4 o;
    o.x = fmaxf(fmaf(hv.x, sc.x, sh.x) + xv.x, 0.f);
    o.y = fmaxf(fmaf(hv.y, sc.y, sh.y) + xv.y, 0.f);
    o.z = fmaxf(fmaf(hv.z, sc.z, sh.z) + xv.z, 0.f);
    o.w = fmaxf(fmaf(hv.w, sc.w, sh.w) + xv.w, 0.f);
    ((float4*)out)[i] = o;
}

extern "C" void kernel_launch(void* const* d_in, const int* in_sizes, int n_in,
                              void* d_out, int out_size, void* d_ws, size_t ws_size,
                              hipStream_t stream) {
    const float* x     = (const float*)d_in[0];
    const int*   eidx  = (const int*)d_in[1];
    const float* W_l   = (const float*)d_in[2];
    const float* b_l   = (const float*)d_in[3];
    const float* W_r   = (const float*)d_in[4];
    const float* gamma = (const float*)d_in[5];
    const float* beta  = (const float*)d_in[6];

    const int D = in_sizes[3];            // 128
    const int N = in_sizes[0] / D;        // 100000
    const int E = in_sizes[1] / 2;        // 1600000

    const int* src = eidx;
    const int* dst = eidx + E;

    // workspace layout (4-byte units)
    int*   deg    = (int*)d_ws;                     // N
    float* stats  = (float*)d_ws + N;               // 256
    int*   offs   = (int*)d_ws + N + 256;           // N+1
    int*   cursor = offs + N + 1;                   // N
    int*   csr    = cursor + N;                     // E
    float* WlT    = (float*)(csr + E);              // 16384
    float* WrT    = WlT + 16384;                    // 16384
    float* scl    = WrT + 16384;                    // 128
    float* shf    = scl + D128;                     // 128

    float* h = (float*)d_out;                       // h lives in d_out

    // zero deg + stats (contiguous)
    hipMemsetAsync(d_ws, 0, (size_t)(N + 256) * sizeof(int), stream);

    transpose_w_kernel<<<128, 256, 0, stream>>>(W_l, W_r, WlT, WrT);

    hist_kernel<<<(E / 4 + 255) / 256 + 1, 256, 0, stream>>>(dst, deg, E);

    scan_kernel<<<1, 1024, 0, stream>>>(deg, offs, cursor, N);

    csr_kernel<<<(E / 4 + 255) / 256 + 1, 256, 0, stream>>>(src, dst, cursor, csr, E);

    gemm_kernel<<<(N + 15) / 16, 256, 0, stream>>>(offs, csr, x, WlT, WrT, b_l, h, N);

    stats_kernel<<<256, 256, 0, stream>>>(h, stats, N);

    bnparam_kernel<<<1, 128, 0, stream>>>(stats, gamma, beta, scl, shf, 1.0f / (float)N);

    {
        long long total4 = (long long)N * D128 / 4;
        finalize_kernel<<<(int)((total4 + 255) / 256), 256, 0, stream>>>(
            h, x, scl, shf, (float*)d_out, total4);
    }
}

// Round 4
// 546.498 us; speedup vs baseline: 5.6643x; 1.3926x over previous
//
#include <hip/hip_runtime.h>
#include <hip/hip_bf16.h>

// ---------------------------------------------------------------------------
// ResidualSAGEBlock: CSR-build (counting sort by dst) -> fused gather-mean +
// dual GEMM -> BatchNorm -> +x -> ReLU.
// N=100000, D=128, E=1600000.
// R2: CSR gather replaced float-atomic scatter (3.3 GB write amp): 3095->812us.
// R3: gemm LDS 48->32KB => 5 blocks/CU; gather unroll x4: 812->761us.
// R4: single-block scan (230us, 1-CU serial) -> 3-kernel multi-block scan.
// ---------------------------------------------------------------------------

#define D128 128

// --- W transpose: WT[k*128+d] = W[d*128+k] (two 128x128 matrices) ----------
__global__ void transpose_w_kernel(const float* __restrict__ Wl,
                                   const float* __restrict__ Wr,
                                   float* __restrict__ WlT,
                                   float* __restrict__ WrT) {
    int idx = blockIdx.x * 256 + threadIdx.x;        // 0 .. 32767
    int m   = idx >> 14;                             // matrix select
    int r   = idx & 16383;
    int k   = r >> 7, d = r & 127;
    if (m == 0) WlT[r] = Wl[d * D128 + k];
    else        WrT[r] = Wr[d * D128 + k];
}

// --- histogram of dst (4 edges/thread, int4 loads) -------------------------
__global__ __launch_bounds__(256) void hist_kernel(const int* __restrict__ dst,
                                                   int* __restrict__ deg, int E) {
    int i = (blockIdx.x * 256 + threadIdx.x) * 4;
    if (i + 3 < E) {
        int4 d4 = *(const int4*)(dst + i);
        atomicAdd(&deg[d4.x], 1);
        atomicAdd(&deg[d4.y], 1);
        atomicAdd(&deg[d4.z], 1);
        atomicAdd(&deg[d4.w], 1);
    } else {
        for (int j = i; j < E; ++j) atomicAdd(&deg[dst[j]], 1);
    }
}

// --- scan stage 1: per-block (1024 elems) sum of deg -----------------------
__global__ __launch_bounds__(256) void partial_kernel(const int* __restrict__ deg,
                                                      int* __restrict__ bsum, int N) {
    int tid  = threadIdx.x;
    int base = blockIdx.x * 1024 + tid * 4;
    int s = 0;
    if (base + 3 < N) {
        int4 v = *(const int4*)(deg + base);
        s = v.x + v.y + v.z + v.w;
    } else {
        for (int i = base; i < N; ++i) s += deg[i];
    }
    __shared__ int red[256];
    red[tid] = s;
    __syncthreads();
    for (int off = 128; off > 0; off >>= 1) {
        if (tid < off) red[tid] += red[tid + off];
        __syncthreads();
    }
    if (tid == 0) bsum[blockIdx.x] = red[0];
}

// --- scan stage 2: exclusive scan of block sums (NB <= 1024); offs[N]=E ----
__global__ __launch_bounds__(1024) void scan_bsum_kernel(
    const int* __restrict__ bsum, int* __restrict__ ebsum,
    int NB, int* __restrict__ offsN, int E) {
    __shared__ int buf[2][1024];
    int t = threadIdx.x;
    int v = (t < NB) ? bsum[t] : 0;
    buf[0][t] = v;
    __syncthreads();
    int pi = 0;
    for (int off = 1; off < 1024; off <<= 1) {
        int u = buf[pi][t];
        if (t >= off) u += buf[pi][t - off];
        buf[pi ^ 1][t] = u;
        __syncthreads();
        pi ^= 1;
    }
    if (t < NB) ebsum[t] = buf[pi][t] - v;   // exclusive prefix
    if (t == 0) *offsN = E;
}

// --- scan stage 3: per-block exclusive scan + ebsum offset -----------------
__global__ __launch_bounds__(256) void scan_final_kernel(
    const int* __restrict__ deg, const int* __restrict__ ebsum,
    int* __restrict__ offs, int* __restrict__ cursor, int N) {
    int tid  = threadIdx.x;
    int base = blockIdx.x * 1024 + tid * 4;
    int d0 = 0, d1 = 0, d2 = 0, d3 = 0;
    if (base + 3 < N) {
        int4 v = *(const int4*)(deg + base);
        d0 = v.x; d1 = v.y; d2 = v.z; d3 = v.w;
    } else {
        if (base     < N) d0 = deg[base];
        if (base + 1 < N) d1 = deg[base + 1];
        if (base + 2 < N) d2 = deg[base + 2];
        if (base + 3 < N) d3 = deg[base + 3];
    }
    int s = d0 + d1 + d2 + d3;
    __shared__ int buf[2][256];
    buf[0][tid] = s;
    __syncthreads();
    int pi = 0;
    for (int off = 1; off < 256; off <<= 1) {
        int u = buf[pi][tid];
        if (tid >= off) u += buf[pi][tid - off];
        buf[pi ^ 1][tid] = u;
        __syncthreads();
        pi ^= 1;
    }
    int pre = buf[pi][tid] - s + ebsum[blockIdx.x];
    if (base + 3 < N) {
        int4 o = make_int4(pre, pre + d0, pre + d0 + d1, pre + d0 + d1 + d2);
        *(int4*)(offs + base)   = o;
        *(int4*)(cursor + base) = o;
    } else {
        int p = pre;
        if (base     < N) { offs[base]     = p; cursor[base]     = p; p += d0; }
        if (base + 1 < N) { offs[base + 1] = p; cursor[base + 1] = p; p += d1; }
        if (base + 2 < N) { offs[base + 2] = p; cursor[base + 2] = p; p += d2; }
        if (base + 3 < N) { offs[base + 3] = p; cursor[base + 3] = p; }
    }
}

// --- CSR fill: csr[pos] = src, pos = cursor[dst]++ (4 edges/thread) --------
__global__ __launch_bounds__(256) void csr_kernel(const int* __restrict__ src,
                                                  const int* __restrict__ dst,
                                                  int* __restrict__ cursor,
                                                  int* __restrict__ csr, int E) {
    int i = (blockIdx.x * 256 + threadIdx.x) * 4;
    if (i + 3 < E) {
        int4 d4 = *(const int4*)(dst + i);
        int4 s4 = *(const int4*)(src + i);
        csr[atomicAdd(&cursor[d4.x], 1)] = s4.x;
        csr[atomicAdd(&cursor[d4.y], 1)] = s4.y;
        csr[atomicAdd(&cursor[d4.z], 1)] = s4.z;
        csr[atomicAdd(&cursor[d4.w], 1)] = s4.w;
    } else {
        for (int j = i; j < E; ++j) csr[atomicAdd(&cursor[dst[j]], 1)] = src[j];
    }
}

// --- fused gather-mean + dual GEMM -----------------------------------------
// 16 rows/block, 256 threads. lane = tid&31 (feature/col group, 4 floats),
// rg = tid>>5 (0..7) owns rows rg and rg+8.
// LDS = 32 KB (sW chunk 16k x 2 mats = 16 KB, sA+sX = 16 KB) -> 5 blocks/CU.
__global__ __launch_bounds__(256, 5) void gemm_kernel(
    const int* __restrict__ offs, const int* __restrict__ csr,
    const float* __restrict__ x, const float* __restrict__ WlT,
    const float* __restrict__ WrT, const float* __restrict__ bl,
    float* __restrict__ h, int N) {
    __shared__ float sWl[16 * D128];
    __shared__ float sWr[16 * D128];
    __shared__ float sA[16][D128];
    __shared__ float sX[16][D128];

    int tid  = threadIdx.x;
    int lane = tid & 31;
    int rg   = tid >> 5;
    int n0   = blockIdx.x * 16;

    // gather-mean rows rg and rg+8 into sA; stage x rows into sX
#pragma unroll
    for (int rr = 0; rr < 2; ++rr) {
        int row = rg + rr * 8;
        int n   = n0 + row;
        float4 a0 = make_float4(0.f, 0.f, 0.f, 0.f);
        float4 a1 = a0, a2 = a0, a3 = a0;
        float4 xv = a0;
        if (n < N) {
            int beg = offs[n], end = offs[n + 1];
            int k = beg;
            for (; k + 3 < end; k += 4) {
                int s0 = csr[k], s1 = csr[k + 1], s2 = csr[k + 2], s3 = csr[k + 3];
                float4 v0 = ((const float4*)(x + (size_t)s0 * D128))[lane];
                float4 v1 = ((const float4*)(x + (size_t)s1 * D128))[lane];
                float4 v2 = ((const float4*)(x + (size_t)s2 * D128))[lane];
                float4 v3 = ((const float4*)(x + (size_t)s3 * D128))[lane];
                a0.x += v0.x; a0.y += v0.y; a0.z += v0.z; a0.w += v0.w;
                a1.x += v1.x; a1.y += v1.y; a1.z += v1.z; a1.w += v1.w;
                a2.x += v2.x; a2.y += v2.y; a2.z += v2.z; a2.w += v2.w;
                a3.x += v3.x; a3.y += v3.y; a3.z += v3.z; a3.w += v3.w;
            }
            for (; k < end; ++k) {
                int s0 = csr[k];
                float4 v0 = ((const float4*)(x + (size_t)s0 * D128))[lane];
                a0.x += v0.x; a0.y += v0.y; a0.z += v0.z; a0.w += v0.w;
            }
            float inv = (end > beg) ? 1.0f / (float)(end - beg) : 0.f;
            a0.x = ((a0.x + a1.x) + (a2.x + a3.x)) * inv;
            a0.y = ((a0.y + a1.y) + (a2.y + a3.y)) * inv;
            a0.z = ((a0.z + a1.z) + (a2.z + a3.z)) * inv;
            a0.w = ((a0.w + a1.w) + (a2.w + a3.w)) * inv;
            xv = ((const float4*)(x + (size_t)n * D128))[lane];
        }
        *(float4*)&sA[row][lane * 4] = a0;
        *(float4*)&sX[row][lane * 4] = xv;
    }

    int d = lane * 4;
    float4 acc0 = *(const float4*)(bl + d);   // row rg
    float4 acc1 = acc0;                       // row rg+8

    for (int k0 = 0; k0 < D128; k0 += 16) {
        __syncthreads();   // first iter: gather done; later: compute done
        // stage 16x128 W tiles (2048 floats each), 8 floats/thread/matrix
        for (int j = tid * 4; j < 16 * D128; j += 1024) {
            *(float4*)&sWl[j] = *(const float4*)(WlT + k0 * D128 + j);
            *(float4*)&sWr[j] = *(const float4*)(WrT + k0 * D128 + j);
        }
        __syncthreads();
#pragma unroll
        for (int kk = 0; kk < 16; kk += 4) {
            float4 a0 = *(const float4*)&sA[rg][k0 + kk];
            float4 a1 = *(const float4*)&sA[rg + 8][k0 + kk];
            float4 x0 = *(const float4*)&sX[rg][k0 + kk];
            float4 x1 = *(const float4*)&sX[rg + 8][k0 + kk];
#pragma unroll
            for (int j = 0; j < 4; ++j) {
                float4 wl = *(const float4*)&sWl[(kk + j) * D128 + d];
                float4 wr = *(const float4*)&sWr[(kk + j) * D128 + d];
                float av0 = ((float*)&a0)[j], xv0 = ((float*)&x0)[j];
                float av1 = ((float*)&a1)[j], xv1 = ((float*)&x1)[j];
                acc0.x = fmaf(av0, wl.x, acc0.x); acc0.y = fmaf(av0, wl.y, acc0.y);
                acc0.z = fmaf(av0, wl.z, acc0.z); acc0.w = fmaf(av0, wl.w, acc0.w);
                acc0.x = fmaf(xv0, wr.x, acc0.x); acc0.y = fmaf(xv0, wr.y, acc0.y);
                acc0.z = fmaf(xv0, wr.z, acc0.z); acc0.w = fmaf(xv0, wr.w, acc0.w);
                acc1.x = fmaf(av1, wl.x, acc1.x); acc1.y = fmaf(av1, wl.y, acc1.y);
                acc1.z = fmaf(av1, wl.z, acc1.z); acc1.w = fmaf(av1, wl.w, acc1.w);
                acc1.x = fmaf(xv1, wr.x, acc1.x); acc1.y = fmaf(xv1, wr.y, acc1.y);
                acc1.z = fmaf(xv1, wr.z, acc1.z); acc1.w = fmaf(xv1, wr.w, acc1.w);
            }
        }
    }

    int n = n0 + rg;
    if (n < N) *(float4*)(h + (size_t)n * D128 + d) = acc0;
    n = n0 + rg + 8;
    if (n < N) *(float4*)(h + (size_t)n * D128 + d) = acc1;
}

// --- BN stats: per-feature sum and sumsq over N rows -----------------------
__global__ __launch_bounds__(256) void stats_kernel(
    const float* __restrict__ h, float* __restrict__ stats, int N) {
    int d    = threadIdx.x & 127;
    int half = threadIdx.x >> 7;
    int chunk = (N + gridDim.x - 1) / gridDim.x;
    int n0 = blockIdx.x * chunk;
    int n1 = min(n0 + chunk, N);
    float s = 0.f, ss = 0.f;
    for (int n = n0 + half; n < n1; n += 2) {
        float v = h[(size_t)n * D128 + d];
        s += v;
        ss += v * v;
    }
    __shared__ float r1[2][D128];
    __shared__ float r2[2][D128];
    r1[half][d] = s;
    r2[half][d] = ss;
    __syncthreads();
    if (half == 0) {
        atomicAdd(&stats[d],        s  + r1[1][d]);
        atomicAdd(&stats[D128 + d], ss + r2[1][d]);
    }
}

// --- BN params: scale/shift per feature ------------------------------------
__global__ void bnparam_kernel(const float* __restrict__ stats,
                               const float* __restrict__ gamma,
                               const float* __restrict__ beta,
                               float* __restrict__ scl, float* __restrict__ shf,
                               float invN) {
    int d = threadIdx.x;
    float mean = stats[d] * invN;
    float var  = stats[D128 + d] * invN - mean * mean;
    float istd = rsqrtf(var + 1e-5f);
    float sc   = gamma[d] * istd;
    scl[d] = sc;
    shf[d] = beta[d] - mean * sc;
}

// --- finalize: out = relu(h*scale + shift + x), float4, in-place on d_out --
__global__ __launch_bounds__(256) void finalize_kernel(
    const float* __restrict__ h, const float* __restrict__ x,
    const float* __restrict__ scl, const float* __restrict__ shf,
    float* __restrict__ out, long long total4) {
    long long i = (long long)blockIdx.x * 256 + threadIdx.x;
    if (i >= total4) return;
    int d = (int)((i * 4) & 127);
    float4 hv = ((const float4*)h)[i];
    float4 xv = ((const float4*)x)[i];
    float4 sc = *(const float4*)(scl + d);
    float4 sh = *(const float4*)(shf + d);
    float4 o;
    o.x = fmaxf(fmaf(hv.x, sc.x, sh.x) + xv.x, 0.f);
    o.y = fmaxf(fmaf(hv.y, sc.y, sh.y) + xv.y, 0.f);
    o.z = fmaxf(fmaf(hv.z, sc.z, sh.z) + xv.z, 0.f);
    o.w = fmaxf(fmaf(hv.w, sc.w, sh.w) + xv.w, 0.f);
    ((float4*)out)[i] = o;
}

extern "C" void kernel_launch(void* const* d_in, const int* in_sizes, int n_in,
                              void* d_out, int out_size, void* d_ws, size_t ws_size,
                              hipStream_t stream) {
    const float* x     = (const float*)d_in[0];
    const int*   eidx  = (const int*)d_in[1];
    const float* W_l   = (const float*)d_in[2];
    const float* b_l   = (const float*)d_in[3];
    const float* W_r   = (const float*)d_in[4];
    const float* gamma = (const float*)d_in[5];
    const float* beta  = (const float*)d_in[6];

    const int D = in_sizes[3];            // 128
    const int N = in_sizes[0] / D;        // 100000
    const int E = in_sizes[1] / 2;        // 1600000

    const int* src = eidx;
    const int* dst = eidx + E;

    const int NB = (N + 1023) / 1024;     // scan blocks (98 for N=100000)

    // workspace layout (4-byte units)
    int*   deg    = (int*)d_ws;                     // N
    float* stats  = (float*)d_ws + N;               // 256
    int*   offs   = (int*)d_ws + N + 256;           // N+1
    int*   cursor = offs + N + 1;                   // N
    int*   csr    = cursor + N;                     // E
    float* WlT    = (float*)(csr + E);              // 16384
    float* WrT    = WlT + 16384;                    // 16384
    float* scl    = WrT + 16384;                    // 128
    float* shf    = scl + D128;                     // 128
    int*   bsum   = (int*)(shf + D128);             // NB
    int*   ebsum  = bsum + NB;                      // NB

    float* h = (float*)d_out;                       // h lives in d_out

    // zero deg + stats (contiguous)
    hipMemsetAsync(d_ws, 0, (size_t)(N + 256) * sizeof(int), stream);

    transpose_w_kernel<<<128, 256, 0, stream>>>(W_l, W_r, WlT, WrT);

    hist_kernel<<<(E / 4 + 255) / 256 + 1, 256, 0, stream>>>(dst, deg, E);

    partial_kernel<<<NB, 256, 0, stream>>>(deg, bsum, N);
    scan_bsum_kernel<<<1, 1024, 0, stream>>>(bsum, ebsum, NB, offs + N, E);
    scan_final_kernel<<<NB, 256, 0, stream>>>(deg, ebsum, offs, cursor, N);

    csr_kernel<<<(E / 4 + 255) / 256 + 1, 256, 0, stream>>>(src, dst, cursor, csr, E);

    gemm_kernel<<<(N + 15) / 16, 256, 0, stream>>>(offs, csr, x, WlT, WrT, b_l, h, N);

    stats_kernel<<<256, 256, 0, stream>>>(h, stats, N);

    bnparam_kernel<<<1, 128, 0, stream>>>(stats, gamma, beta, scl, shf, 1.0f / (float)N);

    {
        long long total4 = (long long)N * D128 / 4;
        finalize_kernel<<<(int)((total4 + 255) / 256), 256, 0, stream>>>(
            h, x, scl, shf, (float*)d_out, total4);
    }
}

// Round 5
// 492.813 us; speedup vs baseline: 6.2813x; 1.1089x over previous
//
#include <hip/hip_runtime.h>
#include <hip/hip_bf16.h>

// ---------------------------------------------------------------------------
// ResidualSAGEBlock: CSR-build -> gather-mean(bf16 agg) -> MFMA bf16 dual GEMM
// (+fused BN partial stats) -> BN -> +x -> ReLU.
// N=100000, D=128, E=1600000.
// R2: CSR gather replaced float-atomic scatter: 3095->812us.
// R3: gemm LDS 48->32KB, 5 blocks/CU: 812->761us.
// R4: multi-block scan (was 230us single-CU): 761->546us.
// R5: split gather (full occupancy) from GEMM; GEMM via mfma_f32_16x16x32_bf16
//     with pre-swizzled B; BN stats fused into MFMA epilogue.
// ---------------------------------------------------------------------------

#define D128 128

typedef short bf16x8 __attribute__((ext_vector_type(8)));
typedef float f32x4  __attribute__((ext_vector_type(4)));

static __device__ __forceinline__ unsigned short f2bf(float f) {
    unsigned u = __builtin_bit_cast(unsigned, f);
    unsigned r = u + 0x7fffu + ((u >> 16) & 1u);   // round-to-nearest-even
    return (unsigned short)(r >> 16);
}

// --- build swizzled bf16 B for MFMA ----------------------------------------
// Bsw[t][c][lane][j] = Wcat[t*32 + (lane>>4)*8 + j][c*16 + (lane&15)]
// where Wcat[k][d] = k<128 ? Wl[d][k] : Wr[d][k-128].   (4096 thr x 8 elems)
__global__ __launch_bounds__(256) void prep_kernel(
    const float* __restrict__ Wl, const float* __restrict__ Wr,
    unsigned short* __restrict__ Bsw) {
    int idx = blockIdx.x * 256 + threadIdx.x;   // 0..4095
    if (idx >= 4096) return;
    int l = idx & 63;
    int c = (idx >> 6) & 7;
    int t = idx >> 9;
    int d = c * 16 + (l & 15);
    int kbase = t * 32 + (l >> 4) * 8;
    unsigned short o[8];
#pragma unroll
    for (int j = 0; j < 8; ++j) {
        int k = kbase + j;
        float v = (k < 128) ? Wl[d * 128 + k] : Wr[d * 128 + (k - 128)];
        o[j] = f2bf(v);
    }
    *(uint4*)(Bsw + (size_t)idx * 8) = *(const uint4*)o;
}

// --- histogram of dst (4 edges/thread) -------------------------------------
__global__ __launch_bounds__(256) void hist_kernel(const int* __restrict__ dst,
                                                   int* __restrict__ deg, int E) {
    int i = (blockIdx.x * 256 + threadIdx.x) * 4;
    if (i + 3 < E) {
        int4 d4 = *(const int4*)(dst + i);
        atomicAdd(&deg[d4.x], 1);
        atomicAdd(&deg[d4.y], 1);
        atomicAdd(&deg[d4.z], 1);
        atomicAdd(&deg[d4.w], 1);
    } else {
        for (int j = i; j < E; ++j) atomicAdd(&deg[dst[j]], 1);
    }
}

// --- scan stage 1: per-block (1024 elems) sum of deg -----------------------
__global__ __launch_bounds__(256) void partial_kernel(const int* __restrict__ deg,
                                                      int* __restrict__ bsum, int N) {
    int tid  = threadIdx.x;
    int base = blockIdx.x * 1024 + tid * 4;
    int s = 0;
    if (base + 3 < N) {
        int4 v = *(const int4*)(deg + base);
        s = v.x + v.y + v.z + v.w;
    } else {
        for (int i = base; i < N; ++i) s += deg[i];
    }
    __shared__ int red[256];
    red[tid] = s;
    __syncthreads();
    for (int off = 128; off > 0; off >>= 1) {
        if (tid < off) red[tid] += red[tid + off];
        __syncthreads();
    }
    if (tid == 0) bsum[blockIdx.x] = red[0];
}

// --- scan stage 2: exclusive scan of block sums (NB <= 1024); offs[N]=E ----
__global__ __launch_bounds__(1024) void scan_bsum_kernel(
    const int* __restrict__ bsum, int* __restrict__ ebsum,
    int NB, int* __restrict__ offsN, int E) {
    __shared__ int buf[2][1024];
    int t = threadIdx.x;
    int v = (t < NB) ? bsum[t] : 0;
    buf[0][t] = v;
    __syncthreads();
    int pi = 0;
    for (int off = 1; off < 1024; off <<= 1) {
        int u = buf[pi][t];
        if (t >= off) u += buf[pi][t - off];
        buf[pi ^ 1][t] = u;
        __syncthreads();
        pi ^= 1;
    }
    if (t < NB) ebsum[t] = buf[pi][t] - v;   // exclusive prefix
    if (t == 0) *offsN = E;
}

// --- scan stage 3: per-block exclusive scan + ebsum offset -----------------
__global__ __launch_bounds__(256) void scan_final_kernel(
    const int* __restrict__ deg, const int* __restrict__ ebsum,
    int* __restrict__ offs, int* __restrict__ cursor, int N) {
    int tid  = threadIdx.x;
    int base = blockIdx.x * 1024 + tid * 4;
    int d0 = 0, d1 = 0, d2 = 0, d3 = 0;
    if (base + 3 < N) {
        int4 v = *(const int4*)(deg + base);
        d0 = v.x; d1 = v.y; d2 = v.z; d3 = v.w;
    } else {
        if (base     < N) d0 = deg[base];
        if (base + 1 < N) d1 = deg[base + 1];
        if (base + 2 < N) d2 = deg[base + 2];
        if (base + 3 < N) d3 = deg[base + 3];
    }
    int s = d0 + d1 + d2 + d3;
    __shared__ int buf[2][256];
    buf[0][tid] = s;
    __syncthreads();
    int pi = 0;
    for (int off = 1; off < 256; off <<= 1) {
        int u = buf[pi][tid];
        if (tid >= off) u += buf[pi][tid - off];
        buf[pi ^ 1][tid] = u;
        __syncthreads();
        pi ^= 1;
    }
    int pre = buf[pi][tid] - s + ebsum[blockIdx.x];
    if (base + 3 < N) {
        int4 o = make_int4(pre, pre + d0, pre + d0 + d1, pre + d0 + d1 + d2);
        *(int4*)(offs + base)   = o;
        *(int4*)(cursor + base) = o;
    } else {
        int p = pre;
        if (base     < N) { offs[base]     = p; cursor[base]     = p; p += d0; }
        if (base + 1 < N) { offs[base + 1] = p; cursor[base + 1] = p; p += d1; }
        if (base + 2 < N) { offs[base + 2] = p; cursor[base + 2] = p; p += d2; }
        if (base + 3 < N) { offs[base + 3] = p; cursor[base + 3] = p; }
    }
}

// --- CSR fill: csr[pos] = src, pos = cursor[dst]++ (4 edges/thread) --------
__global__ __launch_bounds__(256) void csr_kernel(const int* __restrict__ src,
                                                  const int* __restrict__ dst,
                                                  int* __restrict__ cursor,
                                                  int* __restrict__ csr, int E) {
    int i = (blockIdx.x * 256 + threadIdx.x) * 4;
    if (i + 3 < E) {
        int4 d4 = *(const int4*)(dst + i);
        int4 s4 = *(const int4*)(src + i);
        csr[atomicAdd(&cursor[d4.x], 1)] = s4.x;
        csr[atomicAdd(&cursor[d4.y], 1)] = s4.y;
        csr[atomicAdd(&cursor[d4.z], 1)] = s4.z;
        csr[atomicAdd(&cursor[d4.w], 1)] = s4.w;
    } else {
        for (int j = i; j < E; ++j) csr[atomicAdd(&cursor[dst[j]], 1)] = src[j];
    }
}

// --- standalone gather-mean: agg_bf16[n][:] = mean of x[src] rows ----------
// 8 nodes/block (32 lanes each, 4 features/lane). No LDS -> full occupancy.
__global__ __launch_bounds__(256) void gather_kernel(
    const int* __restrict__ offs, const int* __restrict__ csr,
    const float* __restrict__ x, unsigned short* __restrict__ aggb,
    int N, int Npad) {
    int tid  = threadIdx.x;
    int lane = tid & 31;
    int n    = blockIdx.x * 8 + (tid >> 5);
    if (n >= Npad) return;
    float4 a0 = make_float4(0.f, 0.f, 0.f, 0.f);
    float4 a1 = a0, a2 = a0, a3 = a0;
    float inv = 0.f;
    if (n < N) {
        int beg = offs[n], end = offs[n + 1];
        int k = beg;
        for (; k + 3 < end; k += 4) {
            int s0 = csr[k], s1 = csr[k + 1], s2 = csr[k + 2], s3 = csr[k + 3];
            float4 v0 = ((const float4*)(x + (size_t)s0 * D128))[lane];
            float4 v1 = ((const float4*)(x + (size_t)s1 * D128))[lane];
            float4 v2 = ((const float4*)(x + (size_t)s2 * D128))[lane];
            float4 v3 = ((const float4*)(x + (size_t)s3 * D128))[lane];
            a0.x += v0.x; a0.y += v0.y; a0.z += v0.z; a0.w += v0.w;
            a1.x += v1.x; a1.y += v1.y; a1.z += v1.z; a1.w += v1.w;
            a2.x += v2.x; a2.y += v2.y; a2.z += v2.z; a2.w += v2.w;
            a3.x += v3.x; a3.y += v3.y; a3.z += v3.z; a3.w += v3.w;
        }
        for (; k < end; ++k) {
            int s0 = csr[k];
            float4 v0 = ((const float4*)(x + (size_t)s0 * D128))[lane];
            a0.x += v0.x; a0.y += v0.y; a0.z += v0.z; a0.w += v0.w;
        }
        if (end > beg) inv = 1.0f / (float)(end - beg);
    }
    float f0 = ((a0.x + a1.x) + (a2.x + a3.x)) * inv;
    float f1 = ((a0.y + a1.y) + (a2.y + a3.y)) * inv;
    float f2 = ((a0.z + a1.z) + (a2.z + a3.z)) * inv;
    float f3 = ((a0.w + a1.w) + (a2.w + a3.w)) * inv;
    unsigned short o[4] = {f2bf(f0), f2bf(f1), f2bf(f2), f2bf(f3)};
    *(uint2*)(aggb + (size_t)n * D128 + lane * 4) = *(const uint2*)o;
}

// --- MFMA dual GEMM + fused BN partial stats -------------------------------
// Block = 256 thr = 4 waves; wave w owns 32 rows (2 x 16-row A-frags);
// 8 col-tiles of 16 -> full D=128. K=256: ksteps 0-3 read agg_bf16,
// 4-7 read x (fp32 -> bf16 in-flight). Per-wave column sums -> pstat.
__global__ __launch_bounds__(256) void mfma_kernel(
    const unsigned short* __restrict__ aggb, const float* __restrict__ x,
    const unsigned short* __restrict__ Bsw, const float* __restrict__ bl,
    float* __restrict__ h, float* __restrict__ pstat, int N) {
    int tid  = threadIdx.x;
    int w    = tid >> 6;
    int lane = tid & 63;
    int lc   = lane & 15;    // tile col
    int lq   = lane >> 4;    // quarter
    int rowBase = blockIdx.x * 128 + w * 32;

    f32x4 acc[2][8];
#pragma unroll
    for (int c = 0; c < 8; ++c) {
        float b = bl[c * 16 + lc];
        f32x4 v = {b, b, b, b};
        acc[0][c] = v;
        acc[1][c] = v;
    }

    int r0  = rowBase + lc;         // A-frag rows (m = lane&15)
    int r1  = rowBase + 16 + lc;
    int r0c = min(r0, N - 1);       // clamp for x reads (x has exactly N rows)
    int r1c = min(r1, N - 1);

    for (int t = 0; t < 8; ++t) {
        bf16x8 a0, a1;
        if (t < 4) {
            int off = t * 32 + lq * 8;
            a0 = *(const bf16x8*)(aggb + (size_t)r0 * D128 + off);
            a1 = *(const bf16x8*)(aggb + (size_t)r1 * D128 + off);
        } else {
            int off = (t - 4) * 32 + lq * 8;
            const float* p0 = x + (size_t)r0c * D128 + off;
            const float* p1 = x + (size_t)r1c * D128 + off;
            float4 u0 = *(const float4*)p0, u1 = *(const float4*)(p0 + 4);
            float4 v0 = *(const float4*)p1, v1 = *(const float4*)(p1 + 4);
            float tu[8] = {u0.x, u0.y, u0.z, u0.w, u1.x, u1.y, u1.z, u1.w};
            float tv[8] = {v0.x, v0.y, v0.z, v0.w, v1.x, v1.y, v1.z, v1.w};
#pragma unroll
            for (int j = 0; j < 8; ++j) {
                a0[j] = (short)f2bf(tu[j]);
                a1[j] = (short)f2bf(tv[j]);
            }
        }
#pragma unroll
        for (int c = 0; c < 8; ++c) {
            bf16x8 bf = *(const bf16x8*)(Bsw + ((size_t)((t * 8 + c) * 64 + lane)) * 8);
            acc[0][c] = __builtin_amdgcn_mfma_f32_16x16x32_bf16(a0, bf, acc[0][c], 0, 0, 0);
            acc[1][c] = __builtin_amdgcn_mfma_f32_16x16x32_bf16(a1, bf, acc[1][c], 0, 0, 0);
        }
    }

    // epilogue: store h + per-wave column partial stats
    float s[8], ss[8];
#pragma unroll
    for (int c = 0; c < 8; ++c) { s[c] = 0.f; ss[c] = 0.f; }
#pragma unroll
    for (int rh = 0; rh < 2; ++rh) {
#pragma unroll
        for (int reg = 0; reg < 4; ++reg) {
            int row = rowBase + rh * 16 + lq * 4 + reg;   // C-layout row
            if (row < N) {
#pragma unroll
                for (int c = 0; c < 8; ++c) {
                    float v = acc[rh][c][reg];
                    h[(size_t)row * D128 + c * 16 + lc] = v;
                    s[c]  += v;
                    ss[c] += v * v;
                }
            }
        }
    }
#pragma unroll
    for (int c = 0; c < 8; ++c) {
        s[c]  += __shfl_xor(s[c], 16, 64);
        s[c]  += __shfl_xor(s[c], 32, 64);
        ss[c] += __shfl_xor(ss[c], 16, 64);
        ss[c] += __shfl_xor(ss[c], 32, 64);
    }
    if (lq == 0) {
        size_t prow = ((size_t)blockIdx.x * 4 + w) * 256;
#pragma unroll
        for (int c = 0; c < 8; ++c) {
            pstat[prow + c * 16 + lc]       = s[c];
            pstat[prow + 128 + c * 16 + lc] = ss[c];
        }
    }
}

// --- reduce per-wave partial stats -> stats[256] ---------------------------
__global__ __launch_bounds__(256) void statreduce_kernel(
    const float* __restrict__ pstat, float* __restrict__ stats, int NP) {
    int tid = threadIdx.x;
    float loc = 0.f;
    for (int r = blockIdx.x; r < NP; r += gridDim.x)
        loc += pstat[(size_t)r * 256 + tid];
    atomicAdd(&stats[tid], loc);
}

// --- BN params: scale/shift per feature ------------------------------------
__global__ void bnparam_kernel(const float* __restrict__ stats,
                               const float* __restrict__ gamma,
                               const float* __restrict__ beta,
                               float* __restrict__ scl, float* __restrict__ shf,
                               float invN) {
    int d = threadIdx.x;
    float mean = stats[d] * invN;
    float var  = stats[D128 + d] * invN - mean * mean;
    float istd = rsqrtf(var + 1e-5f);
    float sc   = gamma[d] * istd;
    scl[d] = sc;
    shf[d] = beta[d] - mean * sc;
}

// --- finalize: out = relu(h*scale + shift + x), float4, in-place on d_out --
__global__ __launch_bounds__(256) void finalize_kernel(
    const float* __restrict__ h, const float* __restrict__ x,
    const float* __restrict__ scl, const float* __restrict__ shf,
    float* __restrict__ out, long long total4) {
    long long i = (long long)blockIdx.x * 256 + threadIdx.x;
    if (i >= total4) return;
    int d = (int)((i * 4) & 127);
    float4 hv = ((const float4*)h)[i];
    float4 xv = ((const float4*)x)[i];
    float4 sc = *(const float4*)(scl + d);
    float4 sh = *(const float4*)(shf + d);
    float4 o;
    o.x = fmaxf(fmaf(hv.x, sc.x, sh.x) + xv.x, 0.f);
    o.y = fmaxf(fmaf(hv.y, sc.y, sh.y) + xv.y, 0.f);
    o.z = fmaxf(fmaf(hv.z, sc.z, sh.z) + xv.z, 0.f);
    o.w = fmaxf(fmaf(hv.w, sc.w, sh.w) + xv.w, 0.f);
    ((float4*)out)[i] = o;
}

extern "C" void kernel_launch(void* const* d_in, const int* in_sizes, int n_in,
                              void* d_out, int out_size, void* d_ws, size_t ws_size,
                              hipStream_t stream) {
    const float* x     = (const float*)d_in[0];
    const int*   eidx  = (const int*)d_in[1];
    const float* W_l   = (const float*)d_in[2];
    const float* b_l   = (const float*)d_in[3];
    const float* W_r   = (const float*)d_in[4];
    const float* gamma = (const float*)d_in[5];
    const float* beta  = (const float*)d_in[6];

    const int D = in_sizes[3];            // 128
    const int N = in_sizes[0] / D;        // 100000
    const int E = in_sizes[1] / 2;        // 1600000

    const int* src = eidx;
    const int* dst = eidx + E;

    const int NB    = (N + 1023) / 1024;      // scan blocks
    const int NBLK  = (N + 127) / 128;        // mfma blocks (782)
    const int Npad  = NBLK * 128;             // padded rows (100096)
    const int NP    = NBLK * 4;               // pstat rows

    // workspace layout (byte cursor, 64B-aligned chunks)
    char* wp = (char*)d_ws;
    auto alloc = [&](size_t bytes) {
        char* p = wp;
        wp += (bytes + 63) & ~(size_t)63;
        return p;
    };
    int*   deg    = (int*)  alloc((size_t)N * 4 + 256 * 4);   // deg + stats (contig, zeroed)
    float* stats  = (float*)(deg + N);
    int*   offs   = (int*)  alloc((size_t)(N + 1) * 4);
    int*   cursor = (int*)  alloc((size_t)N * 4);
    int*   csr    = (int*)  alloc((size_t)E * 4);             // reused as pstat by mfma
    int*   bsum   = (int*)  alloc((size_t)NB * 4);
    int*   ebsum  = (int*)  alloc((size_t)NB * 4);
    float* scl    = (float*)alloc(128 * 4);
    float* shf    = (float*)alloc(128 * 4);
    unsigned short* Bsw  = (unsigned short*)alloc(4096 * 16); // 8*8*64 frags x 16B
    unsigned short* aggb = (unsigned short*)alloc((size_t)Npad * D128 * 2);
    float* pstat = (float*)csr;                               // mfma runs after gather

    float* h = (float*)d_out;                                 // h lives in d_out

    // zero deg + stats
    hipMemsetAsync(deg, 0, (size_t)(N + 256) * sizeof(int), stream);

    prep_kernel<<<16, 256, 0, stream>>>(W_l, W_r, Bsw);

    hist_kernel<<<(E / 4 + 255) / 256 + 1, 256, 0, stream>>>(dst, deg, E);

    partial_kernel<<<NB, 256, 0, stream>>>(deg, bsum, N);
    scan_bsum_kernel<<<1, 1024, 0, stream>>>(bsum, ebsum, NB, offs + N, E);
    scan_final_kernel<<<NB, 256, 0, stream>>>(deg, ebsum, offs, cursor, N);

    csr_kernel<<<(E / 4 + 255) / 256 + 1, 256, 0, stream>>>(src, dst, cursor, csr, E);

    gather_kernel<<<Npad / 8, 256, 0, stream>>>(offs, csr, x, aggb, N, Npad);

    mfma_kernel<<<NBLK, 256, 0, stream>>>(aggb, x, Bsw, b_l, h, pstat, N);

    statreduce_kernel<<<64, 256, 0, stream>>>(pstat, stats, NP);

    bnparam_kernel<<<1, 128, 0, stream>>>(stats, gamma, beta, scl, shf, 1.0f / (float)N);

    {
        long long total4 = (long long)N * D128 / 4;
        finalize_kernel<<<(int)((total4 + 255) / 256), 256, 0, stream>>>(
            h, x, scl, shf, (float*)d_out, total4);
    }
}